// Round 1
// baseline (1379.765 us; speedup 1.0000x reference)
//
#include <hip/hip_runtime.h>
#include <math.h>

// ---- problem constants --------------------------------------------------
constexpr int kB   = 32;
constexpr int kN   = 512;
constexpr int kM   = 32;
constexpr int kHA  = 64;
constexpr int kHB  = 101;
constexpr int kHO  = 128;            // 2*H_A
constexpr int kNF  = 229;            // 2*H_A + H_B
constexpr int kRows = kB * kN;       // 16384 (b,n) pairs
constexpr long kTRows = (long)kRows * kM;   // 524288 gated rows
constexpr int kNCls = 10;
constexpr float kEps = 1e-5f;
constexpr int kG   = 8;              // (b,n) pairs per block in stats/apply
constexpr int kNB1 = kRows / kG;     // 2048 blocks
constexpr int kWR  = 6;              // Gaussian window radius (filters)
constexpr int kWW  = 2 * kWR + 1;    // 13 taps; tail term < 2e-16

// ---- kernel 0: broadcast atom embeddings --------------------------------
__global__ void k_init_atom(const float* __restrict__ emb, float* __restrict__ atom) {
    int i = blockIdx.x * blockDim.x + threadIdx.x;   // over kRows*kHA
    atom[i] = emb[i & (kN * kHA - 1)];               // kN*kHA = 32768 (pow2)
}

// ---- kernel 1: preA = atom@W1 + b, preB = atom@W2 -----------------------
__global__ __launch_bounds__(256) void k_pre(const float* __restrict__ atom,
                                             const float* __restrict__ W,
                                             const float* __restrict__ bias,
                                             float* __restrict__ preA,
                                             float* __restrict__ preB) {
    __shared__ float sA[8 * kHA];
    int r0 = blockIdx.x * 8;
    int t = threadIdx.x;
    sA[t]       = atom[r0 * kHA + t];
    sA[t + 256] = atom[r0 * kHA + t + 256];
    __syncthreads();
    int h = t & 127, half = t >> 7;
    float bh = bias[h];
    for (int rr = 0; rr < 4; ++rr) {
        int r = half * 4 + rr;
        float accA = bh, accB = 0.f;
        const float* arow = &sA[r * kHA];
        #pragma unroll
        for (int k = 0; k < kHA; ++k) {
            float a = arow[k];
            accA = fmaf(a, W[k * kHO + h], accA);
            accB = fmaf(a, W[(kHA + k) * kHO + h], accB);
        }
        preA[(r0 + r) * kHO + h] = accA;
        preB[(r0 + r) * kHO + h] = accB;
    }
}

// ---- kernel 2: BN1 stats pass (sum / sumsq per channel, block partials) --
__global__ __launch_bounds__(256) void k_stats1(const float* __restrict__ dist,
                                                const int* __restrict__ nbrs,
                                                const float* __restrict__ preA,
                                                const float* __restrict__ preB,
                                                const float* __restrict__ W3,
                                                float* __restrict__ part1) {
    __shared__ float wv[kM][kWW];
    __shared__ int   kcs[kM];
    __shared__ int   rowoff[kM];
    __shared__ float red[512];
    int t = threadIdx.x;
    int h = t & 127, half = t >> 7;
    float S = 0.f, SS = 0.f;
    for (int g = 0; g < kG; ++g) {
        int p = blockIdx.x * kG + g;
        int b = p >> 9;                       // N = 512
        __syncthreads();
        if (t < kM) {
            int m = t;
            float d = dist[p * kM + m];
            int kc = (int)floorf(d * 10.f + 0.5f);
            kcs[m] = kc;
            rowoff[m] = ((b << 9) + nbrs[p * kM + m]) * kHO;
            #pragma unroll
            for (int j = 0; j < kWW; ++j) {
                int k = kc - kWR + j;
                int kk = min(max(k, 0), kHB - 1);
                float df = d - 0.1f * kk;
                wv[m][j] = (k == kk) ? __expf(-df * df * 100.f) : 0.f;
            }
        }
        __syncthreads();
        float pa = preA[p * kHO + h];
        for (int mi = 0; mi < 16; ++mi) {
            int m = half * 16 + mi;
            float x = pa + preB[rowoff[m] + h];
            int kc = kcs[m];
            #pragma unroll
            for (int j = 0; j < kWW; ++j) {
                int kk = min(max(kc - kWR + j, 0), kHB - 1);
                x = fmaf(wv[m][j], W3[kk * kHO + h], x);
            }
            S += x;
            SS = fmaf(x, x, SS);
        }
    }
    red[t] = S; red[256 + t] = SS;
    __syncthreads();
    if (half == 0) {
        part1[blockIdx.x * 256 + h]       = red[h] + red[128 + h];
        part1[blockIdx.x * 256 + 128 + h] = red[256 + h] + red[256 + 128 + h];
    }
}

// ---- kernel 2b: reduce BN1 partials -> per-channel scale/shift ----------
__global__ __launch_bounds__(64) void k_bn1(const float* __restrict__ part1,
                                            const float* __restrict__ g,
                                            const float* __restrict__ bb,
                                            float* __restrict__ sc) {
    int h = blockIdx.x;        // 0..127
    int t = threadIdx.x;
    float S = 0.f, SS = 0.f;
    for (int r = t; r < kNB1; r += 64) {
        S  += part1[r * 256 + h];
        SS += part1[r * 256 + 128 + h];
    }
    for (int o = 32; o; o >>= 1) { S += __shfl_down(S, o); SS += __shfl_down(SS, o); }
    if (t == 0) {
        float inv = 1.f / (float)kTRows;
        float mu = S * inv;
        float var = SS * inv - mu * mu;
        float scale = g[h] * rsqrtf(var + kEps);
        sc[h] = scale;
        sc[128 + h] = bb[h] - mu * scale;
    }
}

// ---- kernel 3: apply BN1, sigmoid*relu, sum over m; BN2 partials --------
__global__ __launch_bounds__(256) void k_apply1(const float* __restrict__ dist,
                                                const int* __restrict__ nbrs,
                                                const float* __restrict__ preA,
                                                const float* __restrict__ preB,
                                                const float* __restrict__ W3,
                                                const float* __restrict__ sc,
                                                float* __restrict__ summed,
                                                float* __restrict__ part2) {
    __shared__ float wv[kM][kWW];
    __shared__ int   kcs[kM];
    __shared__ int   rowoff[kM];
    __shared__ float red[256];
    int t = threadIdx.x;
    int hq = t & 63, q = t >> 6;
    float scf = sc[hq],      shf = sc[128 + hq];
    float scc = sc[64 + hq], shc = sc[192 + hq];
    float S2 = 0.f, SS2 = 0.f;
    for (int g = 0; g < kG; ++g) {
        int p = blockIdx.x * kG + g;
        int b = p >> 9;
        __syncthreads();
        if (t < kM) {
            int m = t;
            float d = dist[p * kM + m];
            int kc = (int)floorf(d * 10.f + 0.5f);
            kcs[m] = kc;
            rowoff[m] = ((b << 9) + nbrs[p * kM + m]) * kHO;
            #pragma unroll
            for (int j = 0; j < kWW; ++j) {
                int k = kc - kWR + j;
                int kk = min(max(k, 0), kHB - 1);
                float df = d - 0.1f * kk;
                wv[m][j] = (k == kk) ? __expf(-df * df * 100.f) : 0.f;
            }
        }
        __syncthreads();
        float paf = preA[p * kHO + hq];
        float pac = preA[p * kHO + 64 + hq];
        float s = 0.f;
        for (int mi = 0; mi < 8; ++mi) {
            int m = q * 8 + mi;
            int ro = rowoff[m];
            float xf = paf + preB[ro + hq];
            float xc = pac + preB[ro + 64 + hq];
            int kc = kcs[m];
            #pragma unroll
            for (int j = 0; j < kWW; ++j) {
                int kk = min(max(kc - kWR + j, 0), kHB - 1);
                float w = wv[m][j];
                xf = fmaf(w, W3[kk * kHO + hq], xf);
                xc = fmaf(w, W3[kk * kHO + 64 + hq], xc);
            }
            float yf = xf * scf + shf;
            float yc = xc * scc + shc;
            float sig = 1.f / (1.f + __expf(-yf));
            s += sig * fmaxf(yc, 0.f);
        }
        red[t] = s;
        __syncthreads();
        if (q == 0) {
            float v = red[hq] + red[64 + hq] + red[128 + hq] + red[192 + hq];
            summed[p * kHA + hq] = v;
            S2 += v;
            SS2 = fmaf(v, v, SS2);
        }
    }
    if (q == 0) {
        part2[blockIdx.x * kHO + hq]      = S2;
        part2[blockIdx.x * kHO + 64 + hq] = SS2;
    }
}

// ---- kernel 3b: reduce BN2 partials -> scale/shift ----------------------
__global__ __launch_bounds__(64) void k_bn2(const float* __restrict__ part2,
                                            const float* __restrict__ g,
                                            const float* __restrict__ bb,
                                            float* __restrict__ sc) {
    int h = blockIdx.x;        // 0..63
    int t = threadIdx.x;
    float S = 0.f, SS = 0.f;
    for (int r = t; r < kNB1; r += 64) {
        S  += part2[r * kHO + h];
        SS += part2[r * kHO + 64 + h];
    }
    for (int o = 32; o; o >>= 1) { S += __shfl_down(S, o); SS += __shfl_down(SS, o); }
    if (t == 0) {
        float inv = 1.f / (float)kRows;
        float mu = S * inv;
        float var = SS * inv - mu * mu;
        float scale = g[h] * rsqrtf(var + kEps);
        sc[h] = scale;
        sc[64 + h] = bb[h] - mu * scale;
    }
}

// ---- kernel 4: residual + relu ------------------------------------------
__global__ void k_resid(float* __restrict__ atom, const float* __restrict__ summed,
                        const float* __restrict__ sc) {
    int i = blockIdx.x * blockDim.x + threadIdx.x;   // kRows*kHA
    int h = i & 63;
    float v = summed[i] * sc[h] + sc[64 + h];
    atom[i] = fmaxf(atom[i] + v, 0.f);
}

// ---- kernel F: pool + classifier + softmax ------------------------------
__global__ __launch_bounds__(256) void k_final(const float* __restrict__ atom,
                                               const float* __restrict__ cw,
                                               const float* __restrict__ cb,
                                               float* __restrict__ out) {
    __shared__ float red[256];
    __shared__ float pooled[kHA];
    __shared__ float lg[kNCls];
    int b = blockIdx.x, t = threadIdx.x;
    int h = t & 63, qq = t >> 6;
    float s = 0.f;
    const float* ab = atom + (long)(b * kN) * kHA;
    for (int n = qq * 128; n < qq * 128 + 128; ++n)
        s += fmaxf(ab[n * kHA + h], 0.f);
    red[t] = s;
    __syncthreads();
    if (qq == 0)
        pooled[h] = (red[h] + red[64 + h] + red[128 + h] + red[192 + h]) * (1.f / kN);
    __syncthreads();
    if (t < kNCls) {
        float acc = cb[t];
        #pragma unroll
        for (int k = 0; k < kHA; ++k) acc = fmaf(pooled[k], cw[k * kNCls + t], acc);
        lg[t] = acc;
    }
    __syncthreads();
    if (t == 0) {
        float mx = lg[0];
        for (int c = 1; c < kNCls; ++c) mx = fmaxf(mx, lg[c]);
        float e[kNCls], se = 0.f;
        for (int c = 0; c < kNCls; ++c) { e[c] = __expf(lg[c] - mx); se += e[c]; }
        float inv = 1.f / se;
        for (int c = 0; c < kNCls; ++c) out[b * kNCls + c] = e[c] * inv;
    }
}

// ---- launcher ------------------------------------------------------------
extern "C" void kernel_launch(void* const* d_in, const int* in_sizes, int n_in,
                              void* d_out, int out_size, void* d_ws, size_t ws_size,
                              hipStream_t stream) {
    const float* dist = (const float*)d_in[0];
    const int*   nbrs = (const int*)d_in[1];
    const float* emb  = (const float*)d_in[2];
    const float* fcw  = (const float*)d_in[3];
    const float* fcb  = (const float*)d_in[4];
    const float* bn1g = (const float*)d_in[5];
    const float* bn1b = (const float*)d_in[6];
    const float* bn2g = (const float*)d_in[7];
    const float* bn2b = (const float*)d_in[8];
    const float* clw  = (const float*)d_in[9];
    const float* clb  = (const float*)d_in[10];
    float* out = (float*)d_out;

    // workspace layout (~27 MB of float32), everything written before read
    float* ws     = (float*)d_ws;
    float* atom   = ws;                          // kRows*kHA
    float* preA   = atom + kRows * kHA;          // kRows*kHO
    float* preB   = preA + kRows * kHO;          // kRows*kHO
    float* summed = preB + kRows * kHO;          // kRows*kHA
    float* part1  = summed + kRows * kHA;        // kNB1*256
    float* part2  = part1 + kNB1 * 256;          // kNB1*kHO
    float* bn1sc  = part2 + kNB1 * kHO;          // 256
    float* bn2sc  = bn1sc + 256;                 // 128

    k_init_atom<<<dim3(kRows * kHA / 256), dim3(256), 0, stream>>>(emb, atom);
    for (int l = 0; l < 4; ++l) {
        const float* W  = fcw + (long)l * kNF * kHO;
        const float* W3 = W + 2 * kHA * kHO;     // rows 128..228
        k_pre<<<dim3(kRows / 8), dim3(256), 0, stream>>>(atom, W, fcb + l * kHO, preA, preB);
        k_stats1<<<dim3(kNB1), dim3(256), 0, stream>>>(dist, nbrs, preA, preB, W3, part1);
        k_bn1<<<dim3(kHO), dim3(64), 0, stream>>>(part1, bn1g + l * kHO, bn1b + l * kHO, bn1sc);
        k_apply1<<<dim3(kNB1), dim3(256), 0, stream>>>(dist, nbrs, preA, preB, W3, bn1sc,
                                                       summed, part2);
        k_bn2<<<dim3(kHA), dim3(64), 0, stream>>>(part2, bn2g + l * kHA, bn2b + l * kHA, bn2sc);
        k_resid<<<dim3(kRows * kHA / 256), dim3(256), 0, stream>>>(atom, summed, bn2sc);
    }
    k_final<<<dim3(kB), dim3(256), 0, stream>>>(atom, clw, clb, out);
}

// Round 2
// 810.696 us; speedup vs baseline: 1.7020x; 1.7020x over previous
//
#include <hip/hip_runtime.h>
#include <math.h>

// ---- problem constants --------------------------------------------------
constexpr int kB   = 32;
constexpr int kN   = 512;
constexpr int kM   = 32;
constexpr int kHA  = 64;
constexpr int kHB  = 101;
constexpr int kHO  = 128;            // 2*H_A
constexpr int kNF  = 229;            // 2*H_A + H_B
constexpr int kRows = kB * kN;       // 16384 (b,n) pairs
constexpr long kTRows = (long)kRows * kM;   // 524288 gated rows
constexpr int kNCls = 10;
constexpr float kEps = 1e-5f;
// stats/apply geometry
constexpr int kG    = 16;            // pairs per block
constexpr int kNB   = kRows / kG;    // 1024 blocks
constexpr int kT    = 512;           // threads per block
constexpr int kTaps = 8;             // contiguous Gaussian window (err ~1e-8)

// ---- kernel 0: broadcast atom embeddings --------------------------------
__global__ void k_init_atom(const float* __restrict__ emb, float* __restrict__ atom) {
    int i = blockIdx.x * blockDim.x + threadIdx.x;   // over kRows*kHA
    atom[i] = emb[i & (kN * kHA - 1)];               // kN*kHA = 32768 (pow2)
}

// ---- kernel 1: (optional resid+relu) then preA = atom@W1+b, preB = atom@W2
template<bool RESID>
__global__ __launch_bounds__(256)
void k_pre(const float* __restrict__ atomIn, float* __restrict__ atomOut,
           const float* __restrict__ summed, const float* __restrict__ sc2,
           const float* __restrict__ W, const float* __restrict__ bias,
           float* __restrict__ preA, float* __restrict__ preB) {
    __shared__ float sA[32 * 64];          // 32 rows of atom (post-resid)
    int t = threadIdx.x;
    int r0 = blockIdx.x * 32;
    for (int i = t; i < 32 * 64; i += 256) {
        int r = i >> 6, h = i & 63;
        float v = atomIn[(r0 + r) * 64 + h];
        if (RESID) {
            float x = fmaf(summed[(r0 + r) * 64 + h], sc2[h], sc2[64 + h]);
            v = fmaxf(v + x, 0.f);
            atomOut[(r0 + r) * 64 + h] = v;
        }
        sA[i] = v;
    }
    __syncthreads();
    int cg = t & 31, rg = t >> 5;          // 4 channels x 4 rows per thread
    const float* Wb = W + cg * 4;
    float4 accA[4], accB[4];
    float4 b4 = *(const float4*)&bias[cg * 4];
    #pragma unroll
    for (int r = 0; r < 4; ++r) {
        accA[r] = b4;
        accB[r] = make_float4(0.f, 0.f, 0.f, 0.f);
    }
    for (int k = 0; k < 64; ++k) {
        float4 wA = *(const float4*)&Wb[k * kHO];
        float4 wB = *(const float4*)&Wb[(64 + k) * kHO];
        #pragma unroll
        for (int r = 0; r < 4; ++r) {
            float a = sA[(rg * 4 + r) * 64 + k];
            accA[r].x = fmaf(a, wA.x, accA[r].x);
            accA[r].y = fmaf(a, wA.y, accA[r].y);
            accA[r].z = fmaf(a, wA.z, accA[r].z);
            accA[r].w = fmaf(a, wA.w, accA[r].w);
            accB[r].x = fmaf(a, wB.x, accB[r].x);
            accB[r].y = fmaf(a, wB.y, accB[r].y);
            accB[r].z = fmaf(a, wB.z, accB[r].z);
            accB[r].w = fmaf(a, wB.w, accB[r].w);
        }
    }
    #pragma unroll
    for (int r = 0; r < 4; ++r) {
        int row = r0 + rg * 4 + r;
        *(float4*)&preA[row * kHO + cg * 4] = accA[r];
        *(float4*)&preB[row * kHO + cg * 4] = accB[r];
    }
}

// ---- shared setup: per (pair, m) window weights, gather row offsets ------
__device__ __forceinline__ void setup_tiles(int t, int blk,
        const float* __restrict__ dist, const int* __restrict__ nbrs,
        float (*wv)[kM][kTaps], int (*roff)[kM], int (*wbase)[kM]) {
    int g = t >> 5, m = t & 31;
    int p = blk * kG + g;
    float d = dist[p * kM + m];
    int kc = (int)floorf(d * 10.f);
    int ks = min(max(kc - 3, 0), kHB - kTaps);    // 0..93, taps ks..ks+7
    wbase[g][m] = ks * kHO;
    roff[g][m] = (((p >> 9) << 9) + nbrs[p * kM + m]) * kHO;
    #pragma unroll
    for (int j = 0; j < kTaps; ++j) {
        float dd = d - 0.1f * (float)(ks + j);
        wv[g][m][j] = __expf(-100.f * dd * dd);
    }
}

// ---- shared inner: x[4] = preA + preB[gather] + window . W3s -------------
__device__ __forceinline__ void compute_x(const float* __restrict__ W3s,
        const float* __restrict__ wvp, int wb, int ro, int cg,
        const float* __restrict__ preB, float2 pa01, float2 pa23,
        float& x0, float& x1, float& x2, float& x3) {
    float2 xb01 = *(const float2*)&preB[ro + 2 * cg];
    float2 xb23 = *(const float2*)&preB[ro + 64 + 2 * cg];
    x0 = pa01.x + xb01.x; x1 = pa01.y + xb01.y;
    x2 = pa23.x + xb23.x; x3 = pa23.y + xb23.y;
    float warr[kTaps];
    *(float4*)&warr[0] = *(const float4*)&wvp[0];
    *(float4*)&warr[4] = *(const float4*)&wvp[4];
    const float* base = &W3s[wb + 2 * cg];
    #pragma unroll
    for (int j = 0; j < kTaps; ++j) {
        float2 a = *(const float2*)&base[j * kHO];
        float2 b = *(const float2*)&base[j * kHO + 64];
        x0 = fmaf(warr[j], a.x, x0);
        x1 = fmaf(warr[j], a.y, x1);
        x2 = fmaf(warr[j], b.x, x2);
        x3 = fmaf(warr[j], b.y, x3);
    }
}

// ---- kernel 2: BN1 stats (sum/sumsq per channel, block partials) ---------
__global__ __launch_bounds__(kT, 4)
void k_stats(const float* __restrict__ dist, const int* __restrict__ nbrs,
             const float* __restrict__ preA, const float* __restrict__ preB,
             const float* __restrict__ W3, float* __restrict__ part1) {
    __shared__ float W3s[kHB * kHO];       // 51712 B
    __shared__ float wv[kG][kM][kTaps];    // 16384 B
    __shared__ int   roff[kG][kM];         // 2048 B
    __shared__ int   wbase[kG][kM];        // 2048 B
    __shared__ float red[1024];            // 4096 B
    int t = threadIdx.x;
    for (int i = t; i < kHB * kHO; i += kT) W3s[i] = W3[i];
    setup_tiles(t, blockIdx.x, dist, nbrs, wv, roff, wbase);
    __syncthreads();
    int cg = t & 31, ms = t >> 5;
    float S[4] = {0.f, 0.f, 0.f, 0.f}, SS[4] = {0.f, 0.f, 0.f, 0.f};
    for (int g = 0; g < kG; ++g) {
        int p = blockIdx.x * kG + g;
        float2 pa01 = *(const float2*)&preA[p * kHO + 2 * cg];
        float2 pa23 = *(const float2*)&preA[p * kHO + 64 + 2 * cg];
        #pragma unroll
        for (int mm = 0; mm < 2; ++mm) {
            int m = ms + mm * 16;
            float x0, x1, x2, x3;
            compute_x(W3s, &wv[g][m][0], wbase[g][m], roff[g][m], cg,
                      preB, pa01, pa23, x0, x1, x2, x3);
            S[0] += x0; S[1] += x1; S[2] += x2; S[3] += x3;
            SS[0] = fmaf(x0, x0, SS[0]); SS[1] = fmaf(x1, x1, SS[1]);
            SS[2] = fmaf(x2, x2, SS[2]); SS[3] = fmaf(x3, x3, SS[3]);
        }
    }
    #pragma unroll
    for (int c = 0; c < 4; ++c) {
        S[c]  += __shfl_xor(S[c], 32);
        SS[c] += __shfl_xor(SS[c], 32);
    }
    int w = t >> 6;
    if ((t & 63) < 32)
        *(float4*)&red[(w * 32 + cg) * 4] = make_float4(S[0], S[1], S[2], S[3]);
    __syncthreads();
    if (t < 128) {
        int c = t >> 5, cc = t & 31;
        float s = 0.f;
        #pragma unroll
        for (int ww = 0; ww < 8; ++ww) s += red[(ww * 32 + cc) * 4 + c];
        int ch = (c < 2) ? (2 * cc + c) : (64 + 2 * cc + (c - 2));
        part1[blockIdx.x * 256 + ch] = s;
    }
    __syncthreads();
    if ((t & 63) < 32)
        *(float4*)&red[(w * 32 + cg) * 4] = make_float4(SS[0], SS[1], SS[2], SS[3]);
    __syncthreads();
    if (t < 128) {
        int c = t >> 5, cc = t & 31;
        float s = 0.f;
        #pragma unroll
        for (int ww = 0; ww < 8; ++ww) s += red[(ww * 32 + cc) * 4 + c];
        int ch = (c < 2) ? (2 * cc + c) : (64 + 2 * cc + (c - 2));
        part1[blockIdx.x * 256 + 128 + ch] = s;
    }
}

// ---- kernel 2b: reduce BN1 partials (single block, coalesced cols) -------
__global__ __launch_bounds__(256)
void k_bn1r(const float* __restrict__ part1, const float* __restrict__ g,
            const float* __restrict__ bb, float* __restrict__ sc) {
    __shared__ float red[256];
    int t = threadIdx.x;
    float a0 = 0.f, a1 = 0.f, a2 = 0.f, a3 = 0.f;
    for (int r = 0; r < kNB; r += 4) {
        a0 += part1[(r + 0) * 256 + t];
        a1 += part1[(r + 1) * 256 + t];
        a2 += part1[(r + 2) * 256 + t];
        a3 += part1[(r + 3) * 256 + t];
    }
    red[t] = (a0 + a1) + (a2 + a3);
    __syncthreads();
    if (t < 128) {
        float inv = 1.f / (float)kTRows;
        float mu = red[t] * inv;
        float var = red[128 + t] * inv - mu * mu;
        float scale = g[t] * rsqrtf(var + kEps);
        sc[t] = scale;
        sc[128 + t] = bb[t] - mu * scale;
    }
}

// ---- kernel 3: apply BN1, sigmoid*relu, sum over m; BN2 partials ---------
__global__ __launch_bounds__(kT, 4)
void k_apply(const float* __restrict__ dist, const int* __restrict__ nbrs,
             const float* __restrict__ preA, const float* __restrict__ preB,
             const float* __restrict__ W3, const float* __restrict__ sc,
             float* __restrict__ summed, float* __restrict__ part2) {
    __shared__ float W3s[kHB * kHO];
    __shared__ float wv[kG][kM][kTaps];
    __shared__ int   roff[kG][kM];
    __shared__ int   wbase[kG][kM];
    __shared__ float red[1024];
    int t = threadIdx.x;
    for (int i = t; i < kHB * kHO; i += kT) W3s[i] = W3[i];
    setup_tiles(t, blockIdx.x, dist, nbrs, wv, roff, wbase);
    int cg = t & 31, ms = t >> 5;
    float scf0 = sc[2 * cg],       scf1 = sc[2 * cg + 1];
    float shf0 = sc[128 + 2 * cg], shf1 = sc[128 + 2 * cg + 1];
    float scc0 = sc[64 + 2 * cg],  scc1 = sc[64 + 2 * cg + 1];
    float shc0 = sc[192 + 2 * cg], shc1 = sc[192 + 2 * cg + 1];
    __syncthreads();
    float S2 = 0.f, SS2 = 0.f;     // live in threads t<64
    for (int g = 0; g < kG; ++g) {
        int p = blockIdx.x * kG + g;
        float2 pa01 = *(const float2*)&preA[p * kHO + 2 * cg];
        float2 pa23 = *(const float2*)&preA[p * kHO + 64 + 2 * cg];
        float s0 = 0.f, s1 = 0.f;
        #pragma unroll
        for (int mm = 0; mm < 2; ++mm) {
            int m = ms + mm * 16;
            float x0, x1, x2, x3;
            compute_x(W3s, &wv[g][m][0], wbase[g][m], roff[g][m], cg,
                      preB, pa01, pa23, x0, x1, x2, x3);
            float yf0 = fmaf(x0, scf0, shf0);
            float yf1 = fmaf(x1, scf1, shf1);
            float yc0 = fmaf(x2, scc0, shc0);
            float yc1 = fmaf(x3, scc1, shc1);
            float sg0 = 1.f / (1.f + __expf(-yf0));
            float sg1 = 1.f / (1.f + __expf(-yf1));
            s0 = fmaf(sg0, fmaxf(yc0, 0.f), s0);
            s1 = fmaf(sg1, fmaxf(yc1, 0.f), s1);
        }
        *(float2*)&red[(ms * 32 + cg) * 2] = make_float2(s0, s1);
        __syncthreads();
        if (t < 64) {
            float v = 0.f;
            #pragma unroll
            for (int m2 = 0; m2 < 16; ++m2)
                v += red[(m2 * 32 + (t >> 1)) * 2 + (t & 1)];
            summed[p * kHA + t] = v;
            S2 += v;
            SS2 = fmaf(v, v, SS2);
        }
        __syncthreads();
    }
    if (t < 64) {
        part2[blockIdx.x * kHO + t] = S2;
        part2[blockIdx.x * kHO + 64 + t] = SS2;
    }
}

// ---- kernel 3b: reduce BN2 partials --------------------------------------
__global__ __launch_bounds__(128)
void k_bn2r(const float* __restrict__ part2, const float* __restrict__ g,
            const float* __restrict__ bb, float* __restrict__ sc) {
    __shared__ float red[128];
    int t = threadIdx.x;
    float a0 = 0.f, a1 = 0.f, a2 = 0.f, a3 = 0.f;
    for (int r = 0; r < kNB; r += 4) {
        a0 += part2[(r + 0) * kHO + t];
        a1 += part2[(r + 1) * kHO + t];
        a2 += part2[(r + 2) * kHO + t];
        a3 += part2[(r + 3) * kHO + t];
    }
    red[t] = (a0 + a1) + (a2 + a3);
    __syncthreads();
    if (t < 64) {
        float inv = 1.f / (float)kRows;
        float mu = red[t] * inv;
        float var = red[64 + t] * inv - mu * mu;
        float scale = g[t] * rsqrtf(var + kEps);
        sc[t] = scale;
        sc[64 + t] = bb[t] - mu * scale;
    }
}

// ---- kernel F: fused resid + pool + classifier + softmax -----------------
__global__ __launch_bounds__(1024)
void k_final(const float* __restrict__ atom, const float* __restrict__ summed,
             const float* __restrict__ sc2, const float* __restrict__ cw,
             const float* __restrict__ cb, float* __restrict__ out) {
    __shared__ float red[1024];
    __shared__ float pooled[kHA];
    __shared__ float lg[kNCls];
    int b = blockIdx.x, t = threadIdx.x;
    int h = t & 63, q = t >> 6;            // 16 groups x 32 atoms
    const float* ab = atom + (long)b * kN * kHA;
    const float* sb = summed + (long)b * kN * kHA;
    float scv = sc2[h], shv = sc2[64 + h];
    float s = 0.f;
    for (int n = q * 32; n < q * 32 + 32; ++n) {
        float v = ab[n * 64 + h] + fmaf(sb[n * 64 + h], scv, shv);
        s += fmaxf(v, 0.f);
    }
    red[t] = s;
    __syncthreads();
    if (t < 64) {
        float v = 0.f;
        #pragma unroll
        for (int qq = 0; qq < 16; ++qq) v += red[qq * 64 + t];
        pooled[t] = v * (1.f / kN);
    }
    __syncthreads();
    if (t < kNCls) {
        float acc = cb[t];
        #pragma unroll
        for (int k = 0; k < kHA; ++k) acc = fmaf(pooled[k], cw[k * kNCls + t], acc);
        lg[t] = acc;
    }
    __syncthreads();
    if (t == 0) {
        float mx = lg[0];
        for (int c = 1; c < kNCls; ++c) mx = fmaxf(mx, lg[c]);
        float e[kNCls], se = 0.f;
        for (int c = 0; c < kNCls; ++c) { e[c] = __expf(lg[c] - mx); se += e[c]; }
        float inv = 1.f / se;
        for (int c = 0; c < kNCls; ++c) out[b * kNCls + c] = e[c] * inv;
    }
}

// ---- launcher ------------------------------------------------------------
extern "C" void kernel_launch(void* const* d_in, const int* in_sizes, int n_in,
                              void* d_out, int out_size, void* d_ws, size_t ws_size,
                              hipStream_t stream) {
    const float* dist = (const float*)d_in[0];
    const int*   nbrs = (const int*)d_in[1];
    const float* emb  = (const float*)d_in[2];
    const float* fcw  = (const float*)d_in[3];
    const float* fcb  = (const float*)d_in[4];
    const float* bn1g = (const float*)d_in[5];
    const float* bn1b = (const float*)d_in[6];
    const float* bn2g = (const float*)d_in[7];
    const float* bn2b = (const float*)d_in[8];
    const float* clw  = (const float*)d_in[9];
    const float* clb  = (const float*)d_in[10];
    float* out = (float*)d_out;

    float* ws     = (float*)d_ws;
    float* atom   = ws;                          // kRows*kHA
    float* preA   = atom + kRows * kHA;          // kRows*kHO
    float* preB   = preA + kRows * kHO;          // kRows*kHO
    float* summed = preB + kRows * kHO;          // kRows*kHA
    float* part1  = summed + kRows * kHA;        // kNB*256
    float* part2  = part1 + kNB * 256;           // kNB*kHO
    float* bn1sc  = part2 + kNB * kHO;           // 256
    float* bn2sc  = bn1sc + 256;                 // 128

    k_init_atom<<<dim3(kRows * kHA / 256), dim3(256), 0, stream>>>(emb, atom);
    for (int l = 0; l < 4; ++l) {
        const float* W  = fcw + (long)l * kNF * kHO;
        const float* W3 = W + 2 * kHA * kHO;     // rows 128..228
        if (l == 0)
            k_pre<false><<<dim3(kRows / 32), dim3(256), 0, stream>>>(
                atom, atom, nullptr, nullptr, W, fcb + l * kHO, preA, preB);
        else
            k_pre<true><<<dim3(kRows / 32), dim3(256), 0, stream>>>(
                atom, atom, summed, bn2sc, W, fcb + l * kHO, preA, preB);
        k_stats<<<dim3(kNB), dim3(kT), 0, stream>>>(dist, nbrs, preA, preB, W3, part1);
        k_bn1r<<<dim3(1), dim3(256), 0, stream>>>(part1, bn1g + l * kHO, bn1b + l * kHO, bn1sc);
        k_apply<<<dim3(kNB), dim3(kT), 0, stream>>>(dist, nbrs, preA, preB, W3, bn1sc,
                                                    summed, part2);
        k_bn2r<<<dim3(1), dim3(128), 0, stream>>>(part2, bn2g + l * kHA, bn2b + l * kHA, bn2sc);
    }
    k_final<<<dim3(kB), dim3(1024), 0, stream>>>(atom, summed, bn2sc, clw, clb, out);
}

// Round 4
// 744.590 us; speedup vs baseline: 1.8531x; 1.0888x over previous
//
#include <hip/hip_runtime.h>
#include <math.h>

typedef _Float16 half_t;
typedef __attribute__((ext_vector_type(4))) _Float16 half4;

// ---- problem constants --------------------------------------------------
constexpr int kB   = 32;
constexpr int kN   = 512;
constexpr int kM   = 32;
constexpr int kHA  = 64;
constexpr int kHB  = 101;
constexpr int kHO  = 128;            // 2*H_A
constexpr int kNF  = 229;            // 2*H_A + H_B
constexpr int kRows = kB * kN;       // 16384 (b,n) pairs
constexpr long kTRows = (long)kRows * kM;   // 524288 gated rows
constexpr int kNCls = 10;
constexpr float kEps = 1e-5f;
// stats/apply geometry
constexpr int kG    = 8;             // pairs per block
constexpr int kNB   = kRows / kG;    // 2048 blocks (divisible by 8 XCDs)
constexpr int kT    = 512;           // threads per block
constexpr int kTaps = 8;             // contiguous Gaussian window (err ~1e-8)

// perm channel j (0..127) -> original channel. j=4*cg+e maps to
// {2cg, 64+2cg, 2cg+1, 64+2cg+1} so each thread's float4 holds 2 filt/core pairs.
__device__ __forceinline__ int origCh(int j) {
    return ((j & 1) << 6) + ((j >> 2) << 1) + ((j >> 1) & 1);
}

// ---- kernel 0: broadcast atom embeddings --------------------------------
__global__ void k_init_atom(const float* __restrict__ emb, float* __restrict__ atom) {
    int i = blockIdx.x * blockDim.x + threadIdx.x;
    atom[i] = emb[i & (kN * kHA - 1)];
}

// ---- kernel 1: (resid+relu) then preA/preB GEMMs (PERMUTED channel out) --
// Also: block 0 zeroes bn1acc (256 f) and the BN2 accumulator this layer's
// k_apply will atomically accumulate into (zeroBuf, 128 f).
template<bool RESID>
__global__ __launch_bounds__(256)
void k_pre(const float* __restrict__ atomIn, float* __restrict__ atomOut,
           const float* __restrict__ summed, const float* __restrict__ acc2,
           const float* __restrict__ g2, const float* __restrict__ b2,
           const float* __restrict__ W, const float* __restrict__ bias,
           float* __restrict__ preA, float* __restrict__ preB,
           float* __restrict__ bn1acc, float* __restrict__ zeroBuf) {
    __shared__ float sA[32 * 64];
    __shared__ float sc2s[128];
    int t = threadIdx.x;
    if (blockIdx.x == 0) {
        bn1acc[t] = 0.f;                 // 256 threads cover 256 floats
        if (t < 128) zeroBuf[t] = 0.f;
    }
    if (RESID) {
        if (t < 64) {
            float inv = 1.f / (float)kRows;
            float mu = acc2[t] * inv;
            float var = acc2[64 + t] * inv - mu * mu;
            float sc = g2[t] * rsqrtf(var + kEps);
            sc2s[t] = sc;
            sc2s[64 + t] = b2[t] - mu * sc;
        }
        __syncthreads();
    }
    int r0 = blockIdx.x * 32;
    for (int i = t; i < 32 * 64; i += 256) {
        float v = atomIn[r0 * 64 + i];
        if (RESID) {
            int h = i & 63;
            v = fmaxf(v + fmaf(summed[r0 * 64 + i], sc2s[h], sc2s[64 + h]), 0.f);
            atomOut[r0 * 64 + i] = v;
        }
        sA[i] = v;
    }
    __syncthreads();
    int cg = t & 31, rg = t >> 5;
    float2 bb01 = *(const float2*)&bias[2 * cg];
    float2 bb23 = *(const float2*)&bias[64 + 2 * cg];
    float4 accA[4], accB[4];
    #pragma unroll
    for (int r = 0; r < 4; ++r) {
        accA[r] = make_float4(bb01.x, bb23.x, bb01.y, bb23.y);
        accB[r] = make_float4(0.f, 0.f, 0.f, 0.f);
    }
    for (int k = 0; k < 64; ++k) {
        float2 wA01 = *(const float2*)&W[k * kHO + 2 * cg];
        float2 wA23 = *(const float2*)&W[k * kHO + 64 + 2 * cg];
        float2 wB01 = *(const float2*)&W[(64 + k) * kHO + 2 * cg];
        float2 wB23 = *(const float2*)&W[(64 + k) * kHO + 64 + 2 * cg];
        #pragma unroll
        for (int r = 0; r < 4; ++r) {
            float a = sA[(rg * 4 + r) * 64 + k];
            accA[r].x = fmaf(a, wA01.x, accA[r].x);
            accA[r].y = fmaf(a, wA23.x, accA[r].y);
            accA[r].z = fmaf(a, wA01.y, accA[r].z);
            accA[r].w = fmaf(a, wA23.y, accA[r].w);
            accB[r].x = fmaf(a, wB01.x, accB[r].x);
            accB[r].y = fmaf(a, wB23.x, accB[r].y);
            accB[r].z = fmaf(a, wB01.y, accB[r].z);
            accB[r].w = fmaf(a, wB23.y, accB[r].w);
        }
    }
    #pragma unroll
    for (int r = 0; r < 4; ++r) {
        int row = r0 + rg * 4 + r;
        *(float4*)&preA[row * kHO + 4 * cg] = accA[r];
        *(float4*)&preB[row * kHO + 4 * cg] = accB[r];
    }
}

// ---- kernel 2: BN1 stats; atomic per-channel S/SS into bn1acc (perm) -----
__global__ __launch_bounds__(kT, 6)
void k_stats(const float* __restrict__ dist, const int* __restrict__ nbrs,
             const float* __restrict__ preA, const float* __restrict__ preB,
             const float* __restrict__ W3, float* __restrict__ acc) {
    __shared__ half_t W3h[kHB * kHO];      // 25856 B, perm channel order
    __shared__ float wv[kG][kM][kTaps];    // 8192 B
    __shared__ int   roff[kG][kM];         // 1024 B
    __shared__ int   wbase[kG][kM];        // 1024 B
    __shared__ float red[2048];            // 8192 B
    int t = threadIdx.x;
    int lb = (int)(blockIdx.x & 7) * (kNB / 8) + (int)(blockIdx.x >> 3);  // XCD swizzle
    for (int i = t; i < kHB * kHO; i += kT)
        W3h[i] = (half_t)W3[(i & ~127) + origCh(i & 127)];
    if (t < kG * kM) {
        int g = t >> 5, m = t & 31;
        int p = lb * kG + g;
        float d = dist[p * kM + m];
        int kc = (int)floorf(d * 10.f);
        int ks = min(max(kc - 3, 0), kHB - kTaps);
        wbase[g][m] = ks * kHO;
        roff[g][m] = (((p >> 9) << 9) + nbrs[p * kM + m]) * kHO;
        #pragma unroll
        for (int j = 0; j < kTaps; ++j) {
            float dd = d - 0.1f * (float)(ks + j);
            wv[g][m][j] = __expf(-100.f * dd * dd);
        }
    }
    __syncthreads();
    int cg = t & 31, ms = t >> 5;
    float S[4] = {0.f, 0.f, 0.f, 0.f}, SS[4] = {0.f, 0.f, 0.f, 0.f};
    for (int g = 0; g < kG; ++g) {
        int p = lb * kG + g;
        float4 pa = *(const float4*)&preA[p * kHO + 4 * cg];
        #pragma unroll
        for (int mm = 0; mm < 2; ++mm) {
            int m = ms + mm * 16;
            int ro = roff[g][m], wb = wbase[g][m];
            float4 pb = *(const float4*)&preB[ro + 4 * cg];
            float x0 = pa.x + pb.x, x1 = pa.y + pb.y;
            float x2 = pa.z + pb.z, x3 = pa.w + pb.w;
            float warr[kTaps];
            *(float4*)&warr[0] = *(const float4*)&wv[g][m][0];
            *(float4*)&warr[4] = *(const float4*)&wv[g][m][4];
            const half_t* hb = &W3h[wb + 4 * cg];
            #pragma unroll
            for (int j = 0; j < kTaps; ++j) {
                half4 hv = *(const half4*)&hb[j * kHO];
                float w = warr[j];
                x0 = fmaf(w, (float)hv.x, x0);
                x1 = fmaf(w, (float)hv.y, x1);
                x2 = fmaf(w, (float)hv.z, x2);
                x3 = fmaf(w, (float)hv.w, x3);
            }
            S[0] += x0; S[1] += x1; S[2] += x2; S[3] += x3;
            SS[0] = fmaf(x0, x0, SS[0]); SS[1] = fmaf(x1, x1, SS[1]);
            SS[2] = fmaf(x2, x2, SS[2]); SS[3] = fmaf(x3, x3, SS[3]);
        }
    }
    #pragma unroll
    for (int c = 0; c < 4; ++c) {
        S[c]  += __shfl_xor(S[c], 32);
        SS[c] += __shfl_xor(SS[c], 32);
    }
    int w = t >> 6;
    if ((t & 63) < 32) {
        *(float4*)&red[w * 128 + cg * 4] = make_float4(S[0], S[1], S[2], S[3]);
        *(float4*)&red[1024 + w * 128 + cg * 4] = make_float4(SS[0], SS[1], SS[2], SS[3]);
    }
    __syncthreads();
    if (t < 256) {
        int j = t & 127, sel = t >> 7;
        float s = 0.f;
        #pragma unroll
        for (int ww = 0; ww < 8; ++ww) s += red[sel * 1024 + ww * 128 + j];
        atomicAdd(&acc[sel * 128 + j], s);
    }
}

// ---- kernel 3: BN1 inline, sigmoid*relu, sum over m; atomic BN2 stats ----
__global__ __launch_bounds__(kT, 6)
void k_apply(const float* __restrict__ dist, const int* __restrict__ nbrs,
             const float* __restrict__ preA, const float* __restrict__ preB,
             const float* __restrict__ W3, const float* __restrict__ acc,
             const float* __restrict__ g1, const float* __restrict__ b1,
             float* __restrict__ summed, float* __restrict__ acc2) {
    __shared__ half_t W3h[kHB * kHO];
    __shared__ float wv[kG][kM][kTaps];
    __shared__ int   roff[kG][kM];
    __shared__ int   wbase[kG][kM];
    __shared__ float red2[512];
    __shared__ float scP[128], shP[128];
    int t = threadIdx.x;
    int lb = (int)(blockIdx.x & 7) * (kNB / 8) + (int)(blockIdx.x >> 3);
    for (int i = t; i < kHB * kHO; i += kT)
        W3h[i] = (half_t)W3[(i & ~127) + origCh(i & 127)];
    if (t < kG * kM) {
        int g = t >> 5, m = t & 31;
        int p = lb * kG + g;
        float d = dist[p * kM + m];
        int kc = (int)floorf(d * 10.f);
        int ks = min(max(kc - 3, 0), kHB - kTaps);
        wbase[g][m] = ks * kHO;
        roff[g][m] = (((p >> 9) << 9) + nbrs[p * kM + m]) * kHO;
        #pragma unroll
        for (int j = 0; j < kTaps; ++j) {
            float dd = d - 0.1f * (float)(ks + j);
            wv[g][m][j] = __expf(-100.f * dd * dd);
        }
    }
    if (t < 128) {                         // BN1 scale/shift inline (perm order)
        float inv = 1.f / (float)kTRows;
        int oc = origCh(t);
        float mu = acc[t] * inv;
        float var = acc[128 + t] * inv - mu * mu;
        float sc = g1[oc] * rsqrtf(var + kEps);
        scP[t] = sc;
        shP[t] = b1[oc] - mu * sc;
    }
    __syncthreads();
    int cg = t & 31, ms = t >> 5;
    float4 sc4 = *(const float4*)&scP[4 * cg];
    float4 sh4 = *(const float4*)&shP[4 * cg];
    float S2 = 0.f, SS2 = 0.f;             // live in t<64
    for (int g = 0; g < kG; ++g) {
        int p = lb * kG + g;
        float4 pa = *(const float4*)&preA[p * kHO + 4 * cg];
        float s0 = 0.f, s1 = 0.f;
        #pragma unroll
        for (int mm = 0; mm < 2; ++mm) {
            int m = ms + mm * 16;
            int ro = roff[g][m], wb = wbase[g][m];
            float4 pb = *(const float4*)&preB[ro + 4 * cg];
            float x0 = pa.x + pb.x, x1 = pa.y + pb.y;
            float x2 = pa.z + pb.z, x3 = pa.w + pb.w;
            float warr[kTaps];
            *(float4*)&warr[0] = *(const float4*)&wv[g][m][0];
            *(float4*)&warr[4] = *(const float4*)&wv[g][m][4];
            const half_t* hb = &W3h[wb + 4 * cg];
            #pragma unroll
            for (int j = 0; j < kTaps; ++j) {
                half4 hv = *(const half4*)&hb[j * kHO];
                float w = warr[j];
                x0 = fmaf(w, (float)hv.x, x0);
                x1 = fmaf(w, (float)hv.y, x1);
                x2 = fmaf(w, (float)hv.z, x2);
                x3 = fmaf(w, (float)hv.w, x3);
            }
            float yf0 = fmaf(x0, sc4.x, sh4.x);
            float yc0 = fmaf(x1, sc4.y, sh4.y);
            float yf1 = fmaf(x2, sc4.z, sh4.z);
            float yc1 = fmaf(x3, sc4.w, sh4.w);
            float sg0 = 1.f / (1.f + __expf(-yf0));
            float sg1 = 1.f / (1.f + __expf(-yf1));
            s0 = fmaf(sg0, fmaxf(yc0, 0.f), s0);
            s1 = fmaf(sg1, fmaxf(yc1, 0.f), s1);
        }
        s0 += __shfl_xor(s0, 32);
        s1 += __shfl_xor(s1, 32);
        int w = t >> 6;
        if ((t & 63) < 32)
            *(float2*)&red2[w * 64 + cg * 2] = make_float2(s0, s1);
        __syncthreads();
        if (t < 64) {
            float v = 0.f;
            #pragma unroll
            for (int ww = 0; ww < 8; ++ww) v += red2[ww * 64 + t];
            summed[p * kHA + t] = v;
            S2 += v;
            SS2 = fmaf(v, v, SS2);
        }
        __syncthreads();
    }
    if (t < 64) {
        atomicAdd(&acc2[t], S2);
        atomicAdd(&acc2[64 + t], SS2);
    }
}

// ---- kernel F: inline BN2, resid + pool + classifier + softmax -----------
__global__ __launch_bounds__(1024)
void k_final(const float* __restrict__ atom, const float* __restrict__ summed,
             const float* __restrict__ acc2, const float* __restrict__ g2,
             const float* __restrict__ b2, const float* __restrict__ cw,
             const float* __restrict__ cb, float* __restrict__ out) {
    __shared__ float red[1024];
    __shared__ float sc2s[128];
    __shared__ float pooled[kHA];
    __shared__ float lg[kNCls];
    int b = blockIdx.x, t = threadIdx.x;
    if (t < 64) {
        float inv = 1.f / (float)kRows;
        float mu = acc2[t] * inv;
        float var = acc2[64 + t] * inv - mu * mu;
        float sc = g2[t] * rsqrtf(var + kEps);
        sc2s[t] = sc;
        sc2s[64 + t] = b2[t] - mu * sc;
    }
    __syncthreads();
    int h = t & 63, q = t >> 6;
    const float* ab = atom + (long)b * kN * kHA;
    const float* sb = summed + (long)b * kN * kHA;
    float scv = sc2s[h], shv = sc2s[64 + h];
    float s = 0.f;
    for (int n = q * 32; n < q * 32 + 32; ++n) {
        float v = ab[n * 64 + h] + fmaf(sb[n * 64 + h], scv, shv);
        s += fmaxf(v, 0.f);
    }
    red[t] = s;
    __syncthreads();
    if (t < 64) {
        float v = 0.f;
        #pragma unroll
        for (int qq = 0; qq < 16; ++qq) v += red[qq * 64 + t];
        pooled[t] = v * (1.f / kN);
    }
    __syncthreads();
    if (t < kNCls) {
        float a = cb[t];
        #pragma unroll
        for (int k = 0; k < kHA; ++k) a = fmaf(pooled[k], cw[k * kNCls + t], a);
        lg[t] = a;
    }
    __syncthreads();
    if (t == 0) {
        float mx = lg[0];
        for (int c = 1; c < kNCls; ++c) mx = fmaxf(mx, lg[c]);
        float e[kNCls], se = 0.f;
        for (int c = 0; c < kNCls; ++c) { e[c] = __expf(lg[c] - mx); se += e[c]; }
        float inv = 1.f / se;
        for (int c = 0; c < kNCls; ++c) out[b * kNCls + c] = e[c] * inv;
    }
}

// ---- launcher ------------------------------------------------------------
extern "C" void kernel_launch(void* const* d_in, const int* in_sizes, int n_in,
                              void* d_out, int out_size, void* d_ws, size_t ws_size,
                              hipStream_t stream) {
    const float* dist = (const float*)d_in[0];
    const int*   nbrs = (const int*)d_in[1];
    const float* emb  = (const float*)d_in[2];
    const float* fcw  = (const float*)d_in[3];
    const float* fcb  = (const float*)d_in[4];
    const float* bn1g = (const float*)d_in[5];
    const float* bn1b = (const float*)d_in[6];
    const float* bn2g = (const float*)d_in[7];
    const float* bn2b = (const float*)d_in[8];
    const float* clw  = (const float*)d_in[9];
    const float* clb  = (const float*)d_in[10];
    float* out = (float*)d_out;

    float* ws     = (float*)d_ws;
    float* atom   = ws;                          // kRows*kHA
    float* preA   = atom + kRows * kHA;          // kRows*kHO (perm)
    float* preB   = preA + kRows * kHO;          // kRows*kHO (perm)
    float* summed = preB + kRows * kHO;          // kRows*kHA
    float* bn1acc = summed + kRows * kHA;        // 256 (S perm | SS perm)
    float* acc2a  = bn1acc + 256;                // 128 (BN2 S|SS, even layers)
    float* acc2b  = acc2a + 128;                 // 128 (odd layers)

    k_init_atom<<<dim3(kRows * kHA / 256), dim3(256), 0, stream>>>(emb, atom);
    for (int l = 0; l < 4; ++l) {
        const float* W  = fcw + (long)l * kNF * kHO;
        const float* W3 = W + 2 * kHA * kHO;
        float* accW = (l & 1) ? acc2b : acc2a;           // apply[l] writes this
        float* accR = ((l - 1) & 1) ? acc2b : acc2a;     // apply[l-1] wrote this
        if (l == 0)
            k_pre<false><<<dim3(kRows / 32), dim3(256), 0, stream>>>(
                atom, atom, nullptr, nullptr, nullptr, nullptr,
                W, fcb + l * kHO, preA, preB, bn1acc, accW);
        else
            k_pre<true><<<dim3(kRows / 32), dim3(256), 0, stream>>>(
                atom, atom, summed, accR, bn2g + (l - 1) * kHA, bn2b + (l - 1) * kHA,
                W, fcb + l * kHO, preA, preB, bn1acc, accW);
        k_stats<<<dim3(kNB), dim3(kT), 0, stream>>>(dist, nbrs, preA, preB, W3, bn1acc);
        k_apply<<<dim3(kNB), dim3(kT), 0, stream>>>(dist, nbrs, preA, preB, W3, bn1acc,
                                                    bn1g + l * kHO, bn1b + l * kHO,
                                                    summed, accW);
    }
    k_final<<<dim3(kB), dim3(1024), 0, stream>>>(atom, summed, acc2b,
                                                 bn2g + 3 * kHA, bn2b + 3 * kHA,
                                                 clw, clb, out);
}